// Round 5
// baseline (488.715 us; speedup 1.0000x reference)
//
#include <hip/hip_runtime.h>
#include <stdint.h>

// Problem: B=8, S=1024, V=8192, D=256. out[b,s,:] = (x[b,s,:] @ E)*16 + pos[s,:]*any(x[b,s,:])
// GEMM M=8192 K=8192 N=256, A=x (0/1 int32, 256 MB stream), B=emb (bf16 table in ws).
// R5: R3 structure (32-row blocks, 8KB dbuf tiles) + KSPLIT=8 (2048 blocks) +
//     __launch_bounds__(256,6) for 6 blocks/CU residency (more independent DMA streams).

#define K_TOT 8192
#define D_DIM 256
#define KSPLIT 8
#define KCHUNK (K_TOT / KSPLIT)     // 1024
#define BK 64                       // ints of k per LDS tile
#define TROWS 32                    // rows per block
#define NTILES (KCHUNK / BK)        // 16
#define PART_STRIDE (8192u * 256u)  // floats per partial

typedef short  short8  __attribute__((ext_vector_type(8)));
typedef float  floatx4 __attribute__((ext_vector_type(4)));
typedef int    intx4   __attribute__((ext_vector_type(4)));

union S8U { intx4 i; short8 s; };

// ws layout: [0,4MB)    bf16 B-table [c=16][kb=256][lane=64][8]
//            [4,68MB)   fp32 partials [KSPLIT=8][8192][256]
//            [68MB,..)  int rs_part [KSPLIT=8][8192]
#define WS_PART_OFF (4u * 1024u * 1024u)
#define WS_RS_OFF   (68u * 1024u * 1024u)

__device__ __forceinline__ unsigned int bf16_rne(float f) {
    unsigned int u = __float_as_uint(f);
    u += 0x7fffu + ((u >> 16) & 1u);
    return u >> 16;
}

__device__ __forceinline__ void load_lds16(const int* g, int* l) {
    __builtin_amdgcn_global_load_lds((const __attribute__((address_space(1))) unsigned int*)g,
                                     (__attribute__((address_space(3))) unsigned int*)l,
                                     16, 0, 0);
}

// ---- emb [8192][256] fp32 -> fragment-major bf16 table, scaled by sqrt(D)=16 ----
// wsBf[((c*256+kb)*64+l)*8+jj] = bf16(emb[kb*32+(l>>4)*8+jj][c*16+(l&15)] * 16)
__global__ __launch_bounds__(256) void prep_kernel(const float* __restrict__ emb,
                                                   unsigned short* __restrict__ wsBf) {
    int gid = blockIdx.x * 256 + threadIdx.x;
    int l  = gid & 63;
    int kb = (gid >> 6) & 255;
    int c  = gid >> 14;
    int d  = c * 16 + (l & 15);
    int v0 = kb * 32 + (l >> 4) * 8;
    const float* src = emb + (size_t)v0 * D_DIM + d;
    intx4 q;
#pragma unroll
    for (int p = 0; p < 4; ++p) {
        unsigned int u0 = bf16_rne(src[(size_t)(2 * p) * D_DIM] * 16.0f);
        unsigned int u1 = bf16_rne(src[(size_t)(2 * p + 1) * D_DIM] * 16.0f);
        q[p] = (int)(u0 | (u1 << 16));
    }
    *(intx4*)(wsBf + (size_t)gid * 8) = q;
}

// ---- GEMM: grid (256 m-blocks of 32 rows, KSPLIT=8), 256 thr = 4 waves (64-col slices) ----
// LDS tile layout: 16B slot s (s=0..511): row = s>>4, granule (s&15)^(row&7)  [XOR swizzle]
__global__ __launch_bounds__(256, 6) void gemm_kernel(const int* __restrict__ x,
                                                      const unsigned short* __restrict__ wsBf,
                                                      float* __restrict__ part,
                                                      int* __restrict__ rsp) {
    __shared__ int Al[2][2048];    // 2 x 8 KB (32 rows x 64 ints)

    const int m0   = blockIdx.x * TROWS;
    const int kidx = blockIdx.y;
    const int kbeg = kidx * KCHUNK;
    const int t    = threadIdx.x;
    const int wave = t >> 6, lane = t & 63;
    const int quad = lane >> 4, rl = lane & 15;
    const int sx   = rl & 7;                    // read-side swizzle key

    // staging: round 0 slot = t (rows 0..15), round 1 slot = 256+t (rows 16..31, same kof)
    const int row0 = t >> 4;
    const int kof  = (t & 15) ^ (row0 & 7);
    const int* g0 = x + (size_t)(m0 + row0) * K_TOT + kbeg + kof * 4;
    const int* g1 = g0 + (size_t)16 * K_TOT;

    floatx4 acc[2][4];
#pragma unroll
    for (int i = 0; i < 2; ++i)
#pragma unroll
        for (int j = 0; j < 4; ++j) acc[i][j] = (floatx4){0.f, 0.f, 0.f, 0.f};
    int rp[2] = {0, 0};

    const int kbase = kidx * (KCHUNK / 32);     // global 32-int k-block base

    // prologue: stage tile 0 into buf 0
    load_lds16(g0, &Al[0][t * 4]);
    load_lds16(g1, &Al[0][1024 + t * 4]);

    for (int tl = 0; tl < NTILES; ++tl) {
        __syncthreads();                         // buf[tl&1] ready; prior readers done
        if (tl + 1 < NTILES) {
            const int* ga = g0 + (tl + 1) * BK;
            const int* gb = g1 + (tl + 1) * BK;
            int* dst = &Al[(tl + 1) & 1][0];
            load_lds16(ga, dst + t * 4);
            load_lds16(gb, dst + 1024 + t * 4);
        }
        const int* buf = &Al[tl & 1][0];

#pragma unroll
        for (int s = 0; s < 2; ++s) {            // two k32 steps per tile
            const int kb = kbase + tl * 2 + s;
            const unsigned short* bB = wsBf + ((size_t)((wave * 4) * 256 + kb) * 64 + lane) * 8;

            short8 af[2];
#pragma unroll
            for (int i = 0; i < 2; ++i) {
                int ka = (s * 8 + quad * 2) ^ sx;        // slot of ints k..k+3
                int kc = (s * 8 + quad * 2 + 1) ^ sx;    // slot of ints k+4..k+7
                int rowb = (i * 16 + rl) * 16;
                intx4 v0 = *(const intx4*)(buf + (rowb + ka) * 4);
                intx4 v1 = *(const intx4*)(buf + (rowb + kc) * 4);
                int p0 = v0[0] | (v0[1] << 16);
                int p1 = v0[2] | (v0[3] << 16);
                int p2 = v1[0] | (v1[1] << 16);
                int p3 = v1[2] | (v1[3] << 16);
                if (wave == 0) rp[i] += p0 + p1 + p2 + p3;
                S8U u;
                u.i[0] = p0 * 0x3F80;                    // pair*0x3F80 -> two bf16 (1.0/0.0)
                u.i[1] = p1 * 0x3F80;
                u.i[2] = p2 * 0x3F80;
                u.i[3] = p3 * 0x3F80;
                af[i] = u.s;
            }

            // B loaded per-j (keeps VGPR under the 6-waves/SIMD cap; compiler pipelines j+1)
#pragma unroll
            for (int j = 0; j < 4; ++j) {
                short8 bf = ((const S8U*)(bB + (size_t)j * 256 * 512))->s;
#pragma unroll
                for (int i = 0; i < 2; ++i)
                    acc[i][j] = __builtin_amdgcn_mfma_f32_16x16x32_bf16(af[i], bf, acc[i][j], 0, 0, 0);
            }
        }
    }

    // row-sums (wave 0 saw every A element): reduce quads, store per-block (no atomics)
    if (wave == 0) {
#pragma unroll
        for (int i = 0; i < 2; ++i) {
            int cnt = (rp[i] & 0xFFFF) + ((unsigned)rp[i] >> 16);
            cnt += __shfl_xor(cnt, 16);
            cnt += __shfl_xor(cnt, 32);
            if (quad == 0) rsp[(size_t)kidx * 8192 + m0 + i * 16 + rl] = cnt;
        }
    }

    // partial store: C/D layout col=lane&15, row=quad*4+reg (m89-verified)
    float* pk = part + (size_t)kidx * PART_STRIDE;
#pragma unroll
    for (int i = 0; i < 2; ++i) {
#pragma unroll
        for (int j = 0; j < 4; ++j) {
            int col = wave * 64 + j * 16 + rl;
#pragma unroll
            for (int r = 0; r < 4; ++r) {
                int row = m0 + i * 16 + quad * 4 + r;
                pk[(size_t)row * D_DIM + col] = acc[i][j][r];
            }
        }
    }
}

// ---- reduce: out = sum_k part[k] + pos * (sum_k rs[k] > 0) ----
__global__ __launch_bounds__(256) void reduce_kernel(const float* __restrict__ part,
                                                     const int* __restrict__ rsp,
                                                     const float* __restrict__ pos,
                                                     float* __restrict__ out) {
    int gid = blockIdx.x * 256 + threadIdx.x;   // 512K threads, 4 floats each
    size_t base = (size_t)gid * 4;
    int row = gid >> 6;
    floatx4 a = *(const floatx4*)(part + base);
    int rsum = rsp[row];
#pragma unroll
    for (int k = 1; k < KSPLIT; ++k) {
        a += *(const floatx4*)(part + (size_t)k * PART_STRIDE + base);
        rsum += rsp[(size_t)k * 8192 + row];
    }
    if (rsum > 0) {
        int s = row & 1023;                      // m = b*1024 + s
        int col = (gid & 63) * 4;
        a += *(const floatx4*)(pos + (size_t)s * D_DIM + col);
    }
    *(floatx4*)(out + base) = a;
}

extern "C" void kernel_launch(void* const* d_in, const int* in_sizes, int n_in,
                              void* d_out, int out_size, void* d_ws, size_t ws_size,
                              hipStream_t stream) {
    const int*   x   = (const int*)d_in[0];     // [8,1024,8192] int32
    const float* emb = (const float*)d_in[1];   // [8192,256] fp32
    const float* pos = (const float*)d_in[2];   // [1,1024,256] fp32
    float*       out = (float*)d_out;           // [8,1024,256] fp32

    unsigned short* wsBf = (unsigned short*)d_ws;
    float*          part = (float*)((char*)d_ws + WS_PART_OFF);
    int*            rsp  = (int*)((char*)d_ws + WS_RS_OFF);

    prep_kernel<<<dim3(1024), dim3(256), 0, stream>>>(emb, wsBf);
    gemm_kernel<<<dim3(256, KSPLIT), dim3(256), 0, stream>>>(x, wsBf, part, rsp);
    reduce_kernel<<<dim3(2048), dim3(256), 0, stream>>>(part, rsp, pos, out);
}

// Round 6
// 406.406 us; speedup vs baseline: 1.2025x; 1.2025x over previous
//
#include <hip/hip_runtime.h>
#include <stdint.h>

// Problem: B=8, S=1024, V=8192, D=256. out[b,s,:] = (x[b,s,:] @ E)*16 + pos[s,:]*any(x[b,s,:])
// GEMM M=8192 K=8192 N=256, A=x (0/1 int32, 256 MB stream), B=emb (bf16 table in ws).
// R6: R3 structure + per-block K-phase rotation to break HBM channel partition-camping
//     (32 KB row pitch => all rows of a tile alias one channel; same-kidx blocks convoy).

#define K_TOT 8192
#define D_DIM 256
#define KSPLIT 4
#define KCHUNK (K_TOT / KSPLIT)   // 2048
#define BK 64                     // ints of k per tile (256 B per row = 1 interleave granule)
#define TROWS 32                  // rows per block
#define NTILES (KCHUNK / BK)      // 32
#define PART_STRIDE (8192u * 256u)  // floats per partial

typedef short  short8  __attribute__((ext_vector_type(8)));
typedef float  floatx4 __attribute__((ext_vector_type(4)));
typedef int    intx4   __attribute__((ext_vector_type(4)));

union S8U { intx4 i; short8 s; };

// ws layout: [0,4MB) bf16 B-table [c=16][kb=256][lane=64][8]
//            [4MB, 36MB) fp32 partials [KSPLIT][8192][256]
//            [36MB, +32KB*4) int rs_part [KSPLIT][8192]
#define WS_PART_OFF (4u * 1024u * 1024u)
#define WS_RS_OFF   (36u * 1024u * 1024u)

__device__ __forceinline__ unsigned int bf16_rne(float f) {
    unsigned int u = __float_as_uint(f);
    u += 0x7fffu + ((u >> 16) & 1u);
    return u >> 16;
}

__device__ __forceinline__ void load_lds16(const int* g, int* l) {
    __builtin_amdgcn_global_load_lds((const __attribute__((address_space(1))) unsigned int*)g,
                                     (__attribute__((address_space(3))) unsigned int*)l,
                                     16, 0, 0);
}

// ---- emb [8192][256] fp32 -> fragment-major bf16 table, scaled by sqrt(D)=16 ----
// wsBf[((c*256+kb)*64+l)*8+jj] = bf16(emb[kb*32+(l>>4)*8+jj][c*16+(l&15)] * 16)
__global__ __launch_bounds__(256) void prep_kernel(const float* __restrict__ emb,
                                                   unsigned short* __restrict__ wsBf) {
    int gid = blockIdx.x * 256 + threadIdx.x;
    int l  = gid & 63;
    int kb = (gid >> 6) & 255;
    int c  = gid >> 14;
    int d  = c * 16 + (l & 15);
    int v0 = kb * 32 + (l >> 4) * 8;
    const float* src = emb + (size_t)v0 * D_DIM + d;
    intx4 q;
#pragma unroll
    for (int p = 0; p < 4; ++p) {
        unsigned int u0 = bf16_rne(src[(size_t)(2 * p) * D_DIM] * 16.0f);
        unsigned int u1 = bf16_rne(src[(size_t)(2 * p + 1) * D_DIM] * 16.0f);
        q[p] = (int)(u0 | (u1 << 16));
    }
    *(intx4*)(wsBf + (size_t)gid * 8) = q;
}

// ---- GEMM: grid (256 m-blocks of 32 rows, KSPLIT=4), 256 thr = 4 waves (64-col slices) ----
// LDS tile layout: 16B slot s (s=0..511): row = s>>4, granule (s&15)^(row&7)  [XOR swizzle]
// K-tiles visited in rotated order p(tl) = (tl + phase) & 31  [channel decamping]
__global__ __launch_bounds__(256) void gemm_kernel(const int* __restrict__ x,
                                                   const unsigned short* __restrict__ wsBf,
                                                   float* __restrict__ part,
                                                   int* __restrict__ rsp) {
    __shared__ int Al[2][2048];    // 2 x 8KB (32 rows x 64 ints)

    const int m0    = blockIdx.x * TROWS;
    const int kidx  = blockIdx.y;
    const int kbeg  = kidx * KCHUNK;
    const int phase = (blockIdx.x * 7 + blockIdx.y * 9) & (NTILES - 1);
    const int t     = threadIdx.x;
    const int wave  = t >> 6, lane = t & 63;
    const int quad  = lane >> 4, rl = lane & 15;
    const int sx    = rl & 7;                   // read-side swizzle key

    // staging: slot t = rows 0..15, slot 256+t = rows 16..31 (same k-offset per lane)
    const int row0 = t >> 4;
    const int kof  = (t & 15) ^ (row0 & 7);
    const int* g0 = x + (size_t)(m0 + row0) * K_TOT + kbeg + kof * 4;
    const int* g1 = g0 + (size_t)16 * K_TOT;

    floatx4 acc[2][4];
#pragma unroll
    for (int i = 0; i < 2; ++i)
#pragma unroll
        for (int j = 0; j < 4; ++j) acc[i][j] = (floatx4){0.f, 0.f, 0.f, 0.f};
    int rp[2] = {0, 0};

    const int kbase = kidx * (KCHUNK / 32);     // global 32-int k-block base

    // prologue: stage tile p(0) into buf 0
    load_lds16(g0 + phase * BK, &Al[0][t * 4]);
    load_lds16(g1 + phase * BK, &Al[0][1024 + t * 4]);

    for (int tl = 0; tl < NTILES; ++tl) {
        const int pcur = (tl + phase) & (NTILES - 1);
        __syncthreads();                         // buf[tl&1] ready; prior readers done
        if (tl + 1 < NTILES) {
            const int pnx = (tl + 1 + phase) & (NTILES - 1);
            const int* ga = g0 + pnx * BK;
            const int* gb = g1 + pnx * BK;
            int* dst = &Al[(tl + 1) & 1][0];
            load_lds16(ga, dst + t * 4);
            load_lds16(gb, dst + 1024 + t * 4);
        }
        const int* buf = &Al[tl & 1][0];

#pragma unroll
        for (int s = 0; s < 2; ++s) {            // two k32 steps per tile
            const int kb = kbase + pcur * 2 + s;

            short8 bf[4];
#pragma unroll
            for (int j = 0; j < 4; ++j)
                bf[j] = ((const S8U*)(wsBf + ((size_t)((wave * 4 + j) * 256 + kb) * 64 + lane) * 8))->s;

            short8 af[2];
#pragma unroll
            for (int i = 0; i < 2; ++i) {
                int ka = (s * 8 + quad * 2) ^ sx;        // slot of ints k..k+3
                int kc = (s * 8 + quad * 2 + 1) ^ sx;    // slot of ints k+4..k+7
                int rowb = (i * 16 + rl) * 16;
                intx4 v0 = *(const intx4*)(buf + (rowb + ka) * 4);
                intx4 v1 = *(const intx4*)(buf + (rowb + kc) * 4);
                int p0 = v0[0] | (v0[1] << 16);
                int p1 = v0[2] | (v0[3] << 16);
                int p2 = v1[0] | (v1[1] << 16);
                int p3 = v1[2] | (v1[3] << 16);
                if (wave == 0) rp[i] += p0 + p1 + p2 + p3;
                S8U u;
                u.i[0] = p0 * 0x3F80;                    // pair*0x3F80 -> two bf16 (1.0/0.0)
                u.i[1] = p1 * 0x3F80;
                u.i[2] = p2 * 0x3F80;
                u.i[3] = p3 * 0x3F80;
                af[i] = u.s;
            }

#pragma unroll
            for (int i = 0; i < 2; ++i)
#pragma unroll
                for (int j = 0; j < 4; ++j)
                    acc[i][j] = __builtin_amdgcn_mfma_f32_16x16x32_bf16(af[i], bf[j], acc[i][j], 0, 0, 0);
        }
    }

    // row-sums (wave 0 saw every A element): reduce quads, store per-block (no atomics)
    if (wave == 0) {
#pragma unroll
        for (int i = 0; i < 2; ++i) {
            int cnt = (rp[i] & 0xFFFF) + ((unsigned)rp[i] >> 16);
            cnt += __shfl_xor(cnt, 16);
            cnt += __shfl_xor(cnt, 32);
            if (quad == 0) rsp[(size_t)kidx * 8192 + m0 + i * 16 + rl] = cnt;
        }
    }

    // partial store: C/D layout col=lane&15, row=quad*4+reg (m89-verified)
    float* pk = part + (size_t)kidx * PART_STRIDE;
#pragma unroll
    for (int i = 0; i < 2; ++i) {
#pragma unroll
        for (int j = 0; j < 4; ++j) {
            int col = wave * 64 + j * 16 + rl;
#pragma unroll
            for (int r = 0; r < 4; ++r) {
                int row = m0 + i * 16 + quad * 4 + r;
                pk[(size_t)row * D_DIM + col] = acc[i][j][r];
            }
        }
    }
}

// ---- reduce: out = sum_k part[k] + pos * (sum_k rs[k] > 0) ----
__global__ __launch_bounds__(256) void reduce_kernel(const float* __restrict__ part,
                                                     const int* __restrict__ rsp,
                                                     const float* __restrict__ pos,
                                                     float* __restrict__ out) {
    int gid = blockIdx.x * 256 + threadIdx.x;    // 512K threads, 4 floats each
    size_t base = (size_t)gid * 4;
    int row = gid >> 6;
    floatx4 a = *(const floatx4*)(part + base);
    int rsum = rsp[row];
#pragma unroll
    for (int k = 1; k < KSPLIT; ++k) {
        a += *(const floatx4*)(part + (size_t)k * PART_STRIDE + base);
        rsum += rsp[(size_t)k * 8192 + row];
    }
    if (rsum > 0) {
        int s = row & 1023;
        int col = (gid & 63) * 4;
        a += *(const floatx4*)(pos + (size_t)s * D_DIM + col);
    }
    *(floatx4*)(out + base) = a;
}

extern "C" void kernel_launch(void* const* d_in, const int* in_sizes, int n_in,
                              void* d_out, int out_size, void* d_ws, size_t ws_size,
                              hipStream_t stream) {
    const int*   x   = (const int*)d_in[0];     // [8,1024,8192] int32
    const float* emb = (const float*)d_in[1];   // [8192,256] fp32
    const float* pos = (const float*)d_in[2];   // [1,1024,256] fp32
    float*       out = (float*)d_out;           // [8,1024,256] fp32

    unsigned short* wsBf = (unsigned short*)d_ws;
    float*          part = (float*)((char*)d_ws + WS_PART_OFF);
    int*            rsp  = (int*)((char*)d_ws + WS_RS_OFF);

    prep_kernel<<<dim3(1024), dim3(256), 0, stream>>>(emb, wsBf);
    gemm_kernel<<<dim3(256, KSPLIT), dim3(256), 0, stream>>>(x, wsBf, part, rsp);
    reduce_kernel<<<dim3(2048), dim3(256), 0, stream>>>(part, rsp, pos, out);
}